// Round 20
// baseline (658.909 us; speedup 1.0000x reference)
//
#include <hip/hip_runtime.h>
#include <hip/hip_bf16.h>

#define H 128
#define W 256
#define HW (H*W)
#define NC 32
#define ND 32
#define NHID 64

// ---- legacy conv (kept for rf3 COUT=1): 1 px/thread, s_load weights ----
template<int NCO>
__global__ __launch_bounds__(256) void conv3x3(
        const float* __restrict__ in0, const float* __restrict__ in1,
        float* __restrict__ out0, float* __restrict__ out1,
        const float* __restrict__ w, const float* __restrict__ b,
        int CIN, int COUT, int wstride, int dorelu,
        const float* __restrict__ addin, int tpose) {
    __shared__ float tile[2][4][10][35];
    const int tid = threadIdx.x;
    const int zg = (COUT + NCO - 1) / NCO;
    const int img = blockIdx.z / zg;
    const int cog = blockIdx.z % zg;
    const float* in = img ? in1 : in0;
    float* out = img ? out1 : out0;
    const int cobase = cog * NCO;
    int nco = COUT - cobase; if (nco > NCO) nco = NCO;
    const int gx0 = blockIdx.x * 32, gy0 = blockIdx.y * 8;
    const int tx = tid & 31, ty = tid >> 5;

    const int nst = (CIN + 3) >> 2;
    {
        int nch = CIN < 4 ? CIN : 4;
        for (int i = tid; i < nch * 340; i += 256) {
            int ch = i / 340, rem = i % 340;
            int r = rem / 34, cc = rem % 34;
            int gy = gy0 + r - 1, gx = gx0 + cc - 1;
            tile[0][ch][r][cc] = (gy >= 0 && gy < H && gx >= 0 && gx < W)
                                 ? in[(size_t)ch * HW + gy * W + gx] : 0.f;
        }
    }
    __syncthreads();

    float acc[NCO];
#pragma unroll
    for (int i = 0; i < NCO; i++) acc[i] = 0.f;

    for (int s = 0; s < nst; s++) {
        const int c0 = s * 4;
        int nch = CIN - c0; if (nch > 4) nch = 4;
        if (s + 1 < nst) {
            const int c1 = c0 + 4;
            int nch2 = CIN - c1; if (nch2 > 4) nch2 = 4;
            const int nb = (s + 1) & 1;
            for (int i = tid; i < nch2 * 340; i += 256) {
                int ch = i / 340, rem = i % 340;
                int r = rem / 34, cc = rem % 34;
                int gy = gy0 + r - 1, gx = gx0 + cc - 1;
                tile[nb][ch][r][cc] = (gy >= 0 && gy < H && gx >= 0 && gx < W)
                                      ? in[(size_t)(c1 + ch) * HW + gy * W + gx] : 0.f;
            }
        }
        const int cb = s & 1;
        for (int ch = 0; ch < nch; ch++) {
            float v[9];
#pragma unroll
            for (int ky = 0; ky < 3; ky++)
#pragma unroll
                for (int kx = 0; kx < 3; kx++)
                    v[ky * 3 + kx] = tile[cb][ch][ty + ky][tx + kx];
            const float* wrow = w + (size_t)cobase * wstride + (size_t)(c0 + ch) * 9;
#pragma unroll
            for (int co = 0; co < NCO; co++) {
                if (co < nco) {
                    const float* wp = wrow + (size_t)co * wstride;
#pragma unroll
                    for (int k = 0; k < 9; k++) acc[co] += wp[k] * v[k];
                }
            }
        }
        __syncthreads();
    }

    const int gy = gy0 + ty, gx = gx0 + tx;
    const float ad = addin ? addin[gy * W + gx] : 0.f;
    if (tpose) {
        float* op = out + (size_t)(gy * W + gx) * 64 + cobase;
#pragma unroll
        for (int co = 0; co < NCO; co++) {
            if (co < nco) {
                float r = acc[co] + b[cobase + co];
                if (dorelu) r = fmaxf(r, 0.f);
                op[co] = r + ad;
            }
        }
    } else {
#pragma unroll
        for (int co = 0; co < NCO; co++) {
            if (co < nco) {
                float r = acc[co] + b[cobase + co];
                if (dorelu) r = fmaxf(r, 0.f);
                r += ad;
                out[(size_t)(cobase + co) * HW + gy * W + gx] = r;
            }
        }
    }
}

// ---- sconv: lane = (cout 0-31, px-half), wave = 16-px strip of ONE image (img = blockIdx.y).
// Input window (3 rows x 18 cols) is wave-uniform -> s_loads; lane selects its 10-col
// slice by ph (cheap cndmask); weights per-lane VGPR. aconv recipe for COUT=32. relu. ----
template<int CIN>
__global__ __launch_bounds__(256) void sconv(
        const float* __restrict__ in0, const float* __restrict__ in1,
        float* __restrict__ out0, float* __restrict__ out1,
        const float* __restrict__ w, int wstride, const float* __restrict__ b) {
    const int tid = threadIdx.x;
    const int lane = tid & 63;
    const int cout = lane & 31;
    const int ph = lane >> 5;
    const int lw = __builtin_amdgcn_readfirstlane(tid >> 6);
    const int wid = blockIdx.x * 4 + lw;     // 0..2047
    const int y = wid >> 4;
    const int xs = (wid & 15) * 16;
    const bool xL = (xs == 0), xR = (xs == W - 16);
    const float* in = blockIdx.y ? in1 : in0;
    float* out = blockIdx.y ? out1 : out0;
    const float* wl = w + (size_t)cout * wstride;

    float acc[8];
#pragma unroll
    for (int i = 0; i < 8; i++) acc[i] = 0.f;

#pragma unroll 2
    for (int cin = 0; cin < CIN; ++cin) {
        float wv[9];
#pragma unroll
        for (int k = 0; k < 9; k++) wv[k] = wl[cin * 9 + k];
#pragma unroll
        for (int r = 0; r < 3; r++) {
            int yy = y - 1 + r;
            if (yy < 0 || yy >= H) continue;
            const float* rp = in + (size_t)cin * HW + yy * W + xs;
            // wave-uniform 18-col window (cols xs-1 .. xs+16), edge-zeroed -> s_loads
            float w18[18];
            w18[0] = xL ? 0.f : rp[-1];
#pragma unroll
            for (int j = 1; j < 17; j++) w18[j] = rp[j - 1];
            w18[17] = xR ? 0.f : rp[16];
            // per-lane 10-col slice: ph=0 -> cols xs-1..xs+8, ph=1 -> xs+7..xs+16
            float riv[10];
#pragma unroll
            for (int j = 0; j < 10; j++) riv[j] = ph ? w18[j + 8] : w18[j];
#pragma unroll
            for (int kx = 0; kx < 3; kx++)
#pragma unroll
                for (int i = 0; i < 8; i++)
                    acc[i] += wv[r * 3 + kx] * riv[i + kx];
        }
    }
    const float bb = b[cout];
    float* op = out + (size_t)cout * HW + y * W + xs + ph * 8;
    float4 o0, o1;
    o0.x = fmaxf(acc[0] + bb, 0.f); o0.y = fmaxf(acc[1] + bb, 0.f);
    o0.z = fmaxf(acc[2] + bb, 0.f); o0.w = fmaxf(acc[3] + bb, 0.f);
    o1.x = fmaxf(acc[4] + bb, 0.f); o1.y = fmaxf(acc[5] + bb, 0.f);
    o1.z = fmaxf(acc[6] + bb, 0.f); o1.w = fmaxf(acc[7] + bb, 0.f);
    *(float4*)op = o0;
    *(float4*)(op + 4) = o1;
}

// ---- A-conv v2: lane = cout (64), wave = 8-px strip (unchanged from R18) ----
__global__ __launch_bounds__(256) void aconv(
        const float* __restrict__ lf, float* __restrict__ At,
        const float* __restrict__ w, const float* __restrict__ b) {
    const int tid = threadIdx.x;
    const int lane = tid & 63;                                   // = cout
    const int lw = __builtin_amdgcn_readfirstlane(tid >> 6);
    const int wid = blockIdx.x * 4 + lw;
    const int y = wid >> 5;
    const int x0 = (wid & 31) * 8;
    const bool xL = (x0 == 0), xR = (x0 == W - 8);

    const float* wl = w + lane * 297;
    float acc[8];
#pragma unroll
    for (int i = 0; i < 8; i++) acc[i] = 0.f;

#pragma unroll 2
    for (int cin = 0; cin < 32; ++cin) {
        float iv[3][10];
#pragma unroll
        for (int r = 0; r < 3; r++) {
            int yy = y - 1 + r;
            if (yy < 0 || yy >= H) {
#pragma unroll
                for (int q = 0; q < 10; q++) iv[r][q] = 0.f;
            } else {
                const float* rp = lf + (size_t)cin * HW + yy * W;
                if (xL) {
                    iv[r][0] = 0.f;
#pragma unroll
                    for (int q = 1; q < 10; q++) iv[r][q] = rp[q - 1];
                } else if (xR) {
#pragma unroll
                    for (int q = 0; q < 9; q++) iv[r][q] = rp[x0 - 1 + q];
                    iv[r][9] = 0.f;
                } else {
#pragma unroll
                    for (int q = 0; q < 10; q++) iv[r][q] = rp[x0 - 1 + q];
                }
            }
        }
        float wv[9];
#pragma unroll
        for (int k = 0; k < 9; k++) wv[k] = wl[cin * 9 + k];
#pragma unroll
        for (int ky = 0; ky < 3; ky++)
#pragma unroll
            for (int kx = 0; kx < 3; kx++)
#pragma unroll
                for (int i = 0; i < 8; i++)
                    acc[i] += wv[ky * 3 + kx] * iv[ky][i + kx];
    }

    const float bb = b[lane];
    float* op = At + (size_t)(y * W + x0) * 64 + lane;
#pragma unroll
    for (int i = 0; i < 8; i++) op[i * 64] = acc[i] + bb;
}

// ---- fused: per-pixel channel dots + cost volume expand + belief init ----
__global__ void chan_cost(const float* __restrict__ lf, const float* __restrict__ rf,
                          const float* __restrict__ cvw, const float* __restrict__ cvb,
                          float* __restrict__ cost, float* __restrict__ bel) {
    __shared__ float rsS[W];
    const int x = threadIdx.x;
    const int p = blockIdx.x * W + x;
    float ls = 0.f, rs = 0.f;
    for (int c = 0; c < NC; c++) {
        ls += lf[c * HW + p] * cvw[c];
        rs += rf[c * HW + p] * cvw[NC + c];
    }
    rsS[x] = rs;
    ls += cvb[0];
    __syncthreads();
#pragma unroll
    for (int d = 0; d < ND; d++) {
        float cc = ls + (x >= d ? rsS[x - d] : 0.f);
        cost[(size_t)d * HW + p] = cc;
        bel[(size_t)d * HW + p] = cc;
    }
}

// ---- MP iteration v13 (R18, unchanged): SGPR bel + launch_bounds(256,4) ----
#define LOADROW(YC, AR)                                                        \
  {                                                                            \
    if ((YC) >= 0 && (YC) < H) {                                               \
      AR[0] = bp[e0off];                                                       \
      _Pragma("unroll") for (int j = 1; j < 17; j++) AR[j] = bp[(j - 8) * 64]; \
      AR[17] = bp[e17off];                                                     \
    }                                                                          \
    bp += W * 64;                                                              \
  }

#define LOADBEL(Z, BR)                                                         \
  {                                                                            \
    const int z_ = (Z);                                                        \
    if (z_ >= 0 && z_ < H) {                                                   \
      const float* br_ = beld + (size_t)z_ * W + x0;                           \
      BR[0] = xnot0 ? br_[-2] : 0.f;                                           \
      BR[1] = xnot0 ? br_[-1] : 0.f;                                           \
      _Pragma("unroll") for (int q = 0; q < 16; q++) BR[q + 2] = br_[q];       \
      BR[18] = xnotE ? br_[16] : 0.f;                                          \
      BR[19] = xnotE ? br_[17] : 0.f;                                          \
    } else {                                                                   \
      _Pragma("unroll") for (int q = 0; q < 20; q++) BR[q] = 0.f;              \
    }                                                                          \
  }

#define COMPUTE(U, AR, HARR, B0, B1, B2)                                       \
  {                                                                            \
    const int yc_ = y0 + (U);                                                  \
    if (yc_ < 0 || yc_ >= H) {                                                 \
      _Pragma("unroll") for (int j = 0; j < 18; j++) HARR[j] = 0.f;            \
    } else {                                                                   \
      _Pragma("unroll") for (int j = 0; j < 18; j++) {                         \
        float acc_ = AR[j];                                                    \
        acc_ += w1[0] * B0[j] + w1[1] * B0[j + 1] + w1[2] * B0[j + 2];         \
        acc_ += w1[3] * B1[j] + w1[4] * B1[j + 1] + w1[5] * B1[j + 2];         \
        acc_ += w1[6] * B2[j] + w1[7] * B2[j + 1] + w1[8] * B2[j + 2];         \
        HARR[j] = fmaxf(acc_, 0.f);                                            \
      }                                                                        \
      if (x0 == 0) HARR[0] = 0.f;                                              \
      if (x0 == W - 16) HARR[17] = 0.f;                                        \
    }                                                                          \
  }

#define EMIT3(T, HH2, HH1, HH0)                                                \
  {                                                                            \
    _Pragma("unroll") for (int jo = 0; jo < 16; jo++) {                        \
      float pp = w2[0] * HH2[jo] + w2[1] * HH2[jo + 1] + w2[2] * HH2[jo + 2]   \
               + w2[3] * HH1[jo] + w2[4] * HH1[jo + 1] + w2[5] * HH1[jo + 2]   \
               + w2[6] * HH0[jo] + w2[7] * HH0[jo + 1] + w2[8] * HH0[jo + 2];  \
      partW[jo][lane] = pp;                                                    \
    }                                                                          \
    {                                                                          \
      const float4* pr = (const float4*)&partW[pq][qq * 16];                   \
      float cg_ = cost[obase + (size_t)(T) * W];                               \
      float4 v0 = pr[0], v1 = pr[1];                                           \
      float s_ = ((v0.x + v0.y) + (v0.z + v0.w)) +                             \
                 ((v1.x + v1.y) + (v1.z + v1.w));                              \
      float4 v2 = pr[2], v3 = pr[3];                                           \
      s_ += ((v2.x + v2.y) + (v2.z + v2.w)) +                                  \
            ((v3.x + v3.y) + (v3.z + v3.w));                                   \
      s_ += __shfl_xor(s_, 16);                                                \
      s_ += __shfl_xor(s_, 32);                                                \
      if (qq == 0) bout[obase + (size_t)(T) * W] = cg_ + s_ + b2;              \
    }                                                                          \
  }

#define STEP(T, AIN, AOUT, HX2, HX1, HX0, B0, B1, B2, BN, DOLOAD, DOBEL)       \
  {                                                                            \
    if (DOBEL) { LOADBEL(y0 + (T) + 3, BN); }                                  \
    if (DOLOAD) { LOADROW(y0 + (T) + 2, AOUT); }                               \
    COMPUTE((T) + 1, AIN, HX0, B0, B1, B2);                                    \
    EMIT3(T, HX2, HX1, HX0);                                                   \
  }

__global__ __launch_bounds__(256, 4) void mp_iter_fast(
    const float* __restrict__ At,    // [HW][64]
    const float* __restrict__ cost,
    const float* __restrict__ bin,
    float* __restrict__ bout,
    const float* __restrict__ mp_w1,
    const float* __restrict__ mp_w2,
    const float* __restrict__ mp_b2) {
    __shared__ float partS[4][16][68];

    const int tid = threadIdx.x;
    const int lane = tid & 63;       // = hid
    const int lw = __builtin_amdgcn_readfirstlane(tid >> 6);
    float (*partW)[68] = partS[lw];

    const int i = blockIdx.x;
    const int xcd = i & 7;
    const int jj = i >> 3;           // 0..255
    const int ybl = jj & 1;
    const int sl = (jj >> 1) & 15;
    const int d4 = jj >> 5;          // 0..7
    const int d = d4 * 4 + lw;
    const int x0 = sl * 16;
    const int y0 = (xcd + 8 * ybl) * 8;
    const bool xnot0 = (x0 > 0), xnotE = (x0 < W - 16);

    float w1[9], w2[9];
#pragma unroll
    for (int k = 0; k < 9; k++) {
        w1[k] = mp_w1[lane * 297 + 288 + k];
        w2[k] = mp_w2[lane * 9 + k];
    }
    const float b2 = mp_b2[0];

    const float* bp = At + (size_t)(y0 - 1) * (W * 64) + (x0 + 7) * 64 + lane;
    const int e0off  = (x0 == 0)      ? -448 : -512;
    const int e17off = (x0 == W - 16) ?  512 :  576;

    const float* beld = bin + (size_t)d * HW;
    const int pq = lane & 15, qq = lane >> 4;
    const size_t obase = (size_t)d * HW + (size_t)y0 * W + x0 + pq;

    float aA[18], aB[18];
    float hA[18], hB[18], hC[18];
    float bl0[20], bl1[20], bl2[20], bl3[20];

    LOADBEL(y0 - 2, bl0);
    LOADBEL(y0 - 1, bl1);
    LOADBEL(y0,     bl2);
    LOADROW(y0 - 1, aA);
    LOADROW(y0,     aB);
    COMPUTE(-1, aA, hA, bl0, bl1, bl2);
    LOADBEL(y0 + 1, bl3);
    LOADROW(y0 + 1, aA);
    COMPUTE(0, aB, hB, bl1, bl2, bl3);
    LOADBEL(y0 + 2, bl0);

    STEP(0, aA, aB, hA, hB, hC, bl2, bl3, bl0, bl1, 1, 1)
    STEP(1, aB, aA, hB, hC, hA, bl3, bl0, bl1, bl2, 1, 1)
    STEP(2, aA, aB, hC, hA, hB, bl0, bl1, bl2, bl3, 1, 1)
    STEP(3, aB, aA, hA, hB, hC, bl1, bl2, bl3, bl0, 1, 1)
    STEP(4, aA, aB, hB, hC, hA, bl2, bl3, bl0, bl1, 1, 1)
    STEP(5, aB, aA, hC, hA, hB, bl3, bl0, bl1, bl2, 1, 1)
    STEP(6, aA, aB, hA, hB, hC, bl0, bl1, bl2, bl3, 1, 1)
    STEP(7, aB, aA, hB, hC, hA, bl1, bl2, bl3, bl0, 0, 0)
}

// ---------------- softmax over D of -belief + disparity + x4 concat fused ----------------
__global__ void softmax_disp(const float* __restrict__ bel, const float* __restrict__ left,
                             float* __restrict__ disp, float* __restrict__ x4) {
    int p = blockIdx.x * 256 + threadIdx.x;
    if (p >= HW) return;
    float v[ND];
    float m = -1e30f;
#pragma unroll
    for (int d = 0; d < ND; d++) {
        v[d] = -bel[d * HW + p];
        m = fmaxf(m, v[d]);
    }
    float s = 0.f, ws = 0.f;
#pragma unroll
    for (int d = 0; d < ND; d++) {
        float e = __expf(v[d] - m);
        s += e;
        ws += e * (float)d;
    }
    float dv = ws / s;
    disp[p] = dv;
    x4[3 * HW + p] = dv;
    x4[p] = left[p];
    x4[HW + p] = left[HW + p];
    x4[2 * HW + p] = left[2 * HW + p];
}

extern "C" void kernel_launch(void* const* d_in, const int* in_sizes, int n_in,
                              void* d_out, int out_size, void* d_ws, size_t ws_size,
                              hipStream_t stream) {
    const float* left   = (const float*)d_in[0];
    const float* right  = (const float*)d_in[1];
    const float* fe_w1  = (const float*)d_in[2];
    const float* fe_b1  = (const float*)d_in[3];
    const float* fe_w2  = (const float*)d_in[4];
    const float* fe_b2  = (const float*)d_in[5];
    const float* cv_w   = (const float*)d_in[6];
    const float* cv_b   = (const float*)d_in[7];
    const float* mp_w1  = (const float*)d_in[8];
    const float* mp_b1  = (const float*)d_in[9];
    const float* mp_w2  = (const float*)d_in[10];
    const float* mp_b2  = (const float*)d_in[11];
    const float* rf_w1  = (const float*)d_in[12];
    const float* rf_b1  = (const float*)d_in[13];
    const float* rf_w2  = (const float*)d_in[14];
    const float* rf_b2  = (const float*)d_in[15];
    const float* rf_w3  = (const float*)d_in[16];
    const float* rf_b3  = (const float*)d_in[17];
    float* out = (float*)d_out;

    float* ws = (float*)d_ws;
    float* At    = ws;
    float* tmp0  = ws;               // NOTE: tmp0/tmp1 alias At region, consumed before aconv writes At
    float* tmp1  = ws + 1048576;
    float* lf    = ws + 2097152;
    float* rfeat = ws + 3145728;
    float* cost  = ws + 4194304;
    float* bel   = ws + 5242880;
    float* bel2  = ws + 6291456;
    float* disp  = ws + 7405568;
    float* x4    = ws + 7438336;
    float* r1    = ws + 7569408;

    dim3 blk(256);

    // feature extraction: sconv (wave-uniform s_load windows), 2 images via grid.y
    sconv<3><<<dim3(512, 2), blk, 0, stream>>>(left, right, tmp0, tmp1, fe_w1, 27, fe_b1);
    sconv<32><<<dim3(512, 2), blk, 0, stream>>>(tmp0, tmp1, lf, rfeat, fe_w2, 288, fe_b2);

    // A-conv: lane=cout, coalesced transposed write into At [p][hid]
    aconv<<<dim3(1024), blk, 0, stream>>>(lf, At, mp_w1, mp_b1);

    // fused channel-dot + cost expand + belief init
    chan_cost<<<dim3(H), blk, 0, stream>>>(lf, rfeat, cv_w, cv_b, cost, bel);

    // 5 MP iterations — 2048 blocks x 256 threads
    dim3 gmp(2048);
    mp_iter_fast<<<gmp, blk, 0, stream>>>(At, cost, bel,  bel2, mp_w1, mp_w2, mp_b2);
    mp_iter_fast<<<gmp, blk, 0, stream>>>(At, cost, bel2, bel,  mp_w1, mp_w2, mp_b2);
    mp_iter_fast<<<gmp, blk, 0, stream>>>(At, cost, bel,  bel2, mp_w1, mp_w2, mp_b2);
    mp_iter_fast<<<gmp, blk, 0, stream>>>(At, cost, bel2, bel,  mp_w1, mp_w2, mp_b2);
    mp_iter_fast<<<gmp, blk, 0, stream>>>(At, cost, bel,  bel2, mp_w1, mp_w2, mp_b2);

    softmax_disp<<<dim3(HW / 256), blk, 0, stream>>>(bel2, left, disp, x4);

    // refinement: sconv for rf1/rf2 (single image), legacy conv for rf3 + fused residual add
    sconv<4><<<dim3(512, 1), blk, 0, stream>>>(x4, x4, r1, r1, rf_w1, 36, rf_b1);
    sconv<32><<<dim3(512, 1), blk, 0, stream>>>(r1, r1, rfeat, rfeat, rf_w2, 288, rf_b2);
    conv3x3<4><<<dim3(8, 16, 1), blk, 0, stream>>>(rfeat, rfeat, out, out, rf_w3, rf_b3, 32, 1, 288, 0, disp, 0);
}

// Round 21
// 452.281 us; speedup vs baseline: 1.4569x; 1.4569x over previous
//
#include <hip/hip_runtime.h>
#include <hip/hip_bf16.h>

#define H 128
#define W 256
#define HW (H*W)
#define NC 32
#define ND 32
#define NHID 64

// ---- conv3x3: 1 px/thread, s_load weights, dbuf 4-cin stages, NCO couts/block ----
template<int NCO>
__global__ __launch_bounds__(256) void conv3x3(
        const float* __restrict__ in0, const float* __restrict__ in1,
        float* __restrict__ out0, float* __restrict__ out1,
        const float* __restrict__ w, const float* __restrict__ b,
        int CIN, int COUT, int wstride, int dorelu,
        const float* __restrict__ addin, int tpose) {
    __shared__ float tile[2][4][10][35];
    const int tid = threadIdx.x;
    const int zg = (COUT + NCO - 1) / NCO;
    const int img = blockIdx.z / zg;
    const int cog = blockIdx.z % zg;
    const float* in = img ? in1 : in0;
    float* out = img ? out1 : out0;
    const int cobase = cog * NCO;
    int nco = COUT - cobase; if (nco > NCO) nco = NCO;
    const int gx0 = blockIdx.x * 32, gy0 = blockIdx.y * 8;
    const int tx = tid & 31, ty = tid >> 5;

    const int nst = (CIN + 3) >> 2;
    {
        int nch = CIN < 4 ? CIN : 4;
        for (int i = tid; i < nch * 340; i += 256) {
            int ch = i / 340, rem = i % 340;
            int r = rem / 34, cc = rem % 34;
            int gy = gy0 + r - 1, gx = gx0 + cc - 1;
            tile[0][ch][r][cc] = (gy >= 0 && gy < H && gx >= 0 && gx < W)
                                 ? in[(size_t)ch * HW + gy * W + gx] : 0.f;
        }
    }
    __syncthreads();

    float acc[NCO];
#pragma unroll
    for (int i = 0; i < NCO; i++) acc[i] = 0.f;

    for (int s = 0; s < nst; s++) {
        const int c0 = s * 4;
        int nch = CIN - c0; if (nch > 4) nch = 4;
        if (s + 1 < nst) {
            const int c1 = c0 + 4;
            int nch2 = CIN - c1; if (nch2 > 4) nch2 = 4;
            const int nb = (s + 1) & 1;
            for (int i = tid; i < nch2 * 340; i += 256) {
                int ch = i / 340, rem = i % 340;
                int r = rem / 34, cc = rem % 34;
                int gy = gy0 + r - 1, gx = gx0 + cc - 1;
                tile[nb][ch][r][cc] = (gy >= 0 && gy < H && gx >= 0 && gx < W)
                                      ? in[(size_t)(c1 + ch) * HW + gy * W + gx] : 0.f;
            }
        }
        const int cb = s & 1;
        for (int ch = 0; ch < nch; ch++) {
            float v[9];
#pragma unroll
            for (int ky = 0; ky < 3; ky++)
#pragma unroll
                for (int kx = 0; kx < 3; kx++)
                    v[ky * 3 + kx] = tile[cb][ch][ty + ky][tx + kx];
            const float* wrow = w + (size_t)cobase * wstride + (size_t)(c0 + ch) * 9;
#pragma unroll
            for (int co = 0; co < NCO; co++) {
                if (co < nco) {
                    const float* wp = wrow + (size_t)co * wstride;
#pragma unroll
                    for (int k = 0; k < 9; k++) acc[co] += wp[k] * v[k];
                }
            }
        }
        __syncthreads();
    }

    const int gy = gy0 + ty, gx = gx0 + tx;
    const float ad = addin ? addin[gy * W + gx] : 0.f;
    if (tpose) {
        float* op = out + (size_t)(gy * W + gx) * 64 + cobase;
#pragma unroll
        for (int co = 0; co < NCO; co++) {
            if (co < nco) {
                float r = acc[co] + b[cobase + co];
                if (dorelu) r = fmaxf(r, 0.f);
                op[co] = r + ad;
            }
        }
    } else {
#pragma unroll
        for (int co = 0; co < NCO; co++) {
            if (co < nco) {
                float r = acc[co] + b[cobase + co];
                if (dorelu) r = fmaxf(r, 0.f);
                r += ad;
                out[(size_t)(cobase + co) * HW + gy * W + gx] = r;
            }
        }
    }
}

// ---- A-conv v2: lane = cout (64), wave = 8-px strip; wave-uniform s_load inputs ----
__global__ __launch_bounds__(256) void aconv(
        const float* __restrict__ lf, float* __restrict__ At,
        const float* __restrict__ w, const float* __restrict__ b) {
    const int tid = threadIdx.x;
    const int lane = tid & 63;                                   // = cout
    const int lw = __builtin_amdgcn_readfirstlane(tid >> 6);
    const int wid = blockIdx.x * 4 + lw;
    const int y = wid >> 5;
    const int x0 = (wid & 31) * 8;
    const bool xL = (x0 == 0), xR = (x0 == W - 8);

    const float* wl = w + lane * 297;
    float acc[8];
#pragma unroll
    for (int i = 0; i < 8; i++) acc[i] = 0.f;

#pragma unroll 2
    for (int cin = 0; cin < 32; ++cin) {
        float iv[3][10];
#pragma unroll
        for (int r = 0; r < 3; r++) {
            int yy = y - 1 + r;
            if (yy < 0 || yy >= H) {
#pragma unroll
                for (int q = 0; q < 10; q++) iv[r][q] = 0.f;
            } else {
                const float* rp = lf + (size_t)cin * HW + yy * W;
                if (xL) {
                    iv[r][0] = 0.f;
#pragma unroll
                    for (int q = 1; q < 10; q++) iv[r][q] = rp[q - 1];
                } else if (xR) {
#pragma unroll
                    for (int q = 0; q < 9; q++) iv[r][q] = rp[x0 - 1 + q];
                    iv[r][9] = 0.f;
                } else {
#pragma unroll
                    for (int q = 0; q < 10; q++) iv[r][q] = rp[x0 - 1 + q];
                }
            }
        }
        float wv[9];
#pragma unroll
        for (int k = 0; k < 9; k++) wv[k] = wl[cin * 9 + k];
#pragma unroll
        for (int ky = 0; ky < 3; ky++)
#pragma unroll
            for (int kx = 0; kx < 3; kx++)
#pragma unroll
                for (int i = 0; i < 8; i++)
                    acc[i] += wv[ky * 3 + kx] * iv[ky][i + kx];
    }

    const float bb = b[lane];
    float* op = At + (size_t)(y * W + x0) * 64 + lane;
#pragma unroll
    for (int i = 0; i < 8; i++) op[i * 64] = acc[i] + bb;
}

// ---- fused: per-pixel channel dots + cost volume expand + belief init ----
__global__ void chan_cost(const float* __restrict__ lf, const float* __restrict__ rf,
                          const float* __restrict__ cvw, const float* __restrict__ cvb,
                          float* __restrict__ cost, float* __restrict__ bel) {
    __shared__ float rsS[W];
    const int x = threadIdx.x;
    const int p = blockIdx.x * W + x;
    float ls = 0.f, rs = 0.f;
    for (int c = 0; c < NC; c++) {
        ls += lf[c * HW + p] * cvw[c];
        rs += rf[c * HW + p] * cvw[NC + c];
    }
    rsS[x] = rs;
    ls += cvb[0];
    __syncthreads();
#pragma unroll
    for (int d = 0; d < ND; d++) {
        float cc = ls + (x >= d ? rsS[x - d] : 0.f);
        cost[(size_t)d * HW + p] = cc;
        bel[(size_t)d * HW + p] = cc;
    }
}

// ---- MP iteration v13: SGPR bel + launch_bounds(256,4) (VGPR<=64 cliff) ----
#define LOADROW(YC, AR)                                                        \
  {                                                                            \
    if ((YC) >= 0 && (YC) < H) {                                               \
      AR[0] = bp[e0off];                                                       \
      _Pragma("unroll") for (int j = 1; j < 17; j++) AR[j] = bp[(j - 8) * 64]; \
      AR[17] = bp[e17off];                                                     \
    }                                                                          \
    bp += W * 64;                                                              \
  }

#define LOADBEL(Z, BR)                                                         \
  {                                                                            \
    const int z_ = (Z);                                                        \
    if (z_ >= 0 && z_ < H) {                                                   \
      const float* br_ = beld + (size_t)z_ * W + x0;                           \
      BR[0] = xnot0 ? br_[-2] : 0.f;                                           \
      BR[1] = xnot0 ? br_[-1] : 0.f;                                           \
      _Pragma("unroll") for (int q = 0; q < 16; q++) BR[q + 2] = br_[q];       \
      BR[18] = xnotE ? br_[16] : 0.f;                                          \
      BR[19] = xnotE ? br_[17] : 0.f;                                          \
    } else {                                                                   \
      _Pragma("unroll") for (int q = 0; q < 20; q++) BR[q] = 0.f;              \
    }                                                                          \
  }

#define COMPUTE(U, AR, HARR, B0, B1, B2)                                       \
  {                                                                            \
    const int yc_ = y0 + (U);                                                  \
    if (yc_ < 0 || yc_ >= H) {                                                 \
      _Pragma("unroll") for (int j = 0; j < 18; j++) HARR[j] = 0.f;            \
    } else {                                                                   \
      _Pragma("unroll") for (int j = 0; j < 18; j++) {                         \
        float acc_ = AR[j];                                                    \
        acc_ += w1[0] * B0[j] + w1[1] * B0[j + 1] + w1[2] * B0[j + 2];         \
        acc_ += w1[3] * B1[j] + w1[4] * B1[j + 1] + w1[5] * B1[j + 2];         \
        acc_ += w1[6] * B2[j] + w1[7] * B2[j + 1] + w1[8] * B2[j + 2];         \
        HARR[j] = fmaxf(acc_, 0.f);                                            \
      }                                                                        \
      if (x0 == 0) HARR[0] = 0.f;                                              \
      if (x0 == W - 16) HARR[17] = 0.f;                                        \
    }                                                                          \
  }

#define EMIT3(T, HH2, HH1, HH0)                                                \
  {                                                                            \
    _Pragma("unroll") for (int jo = 0; jo < 16; jo++) {                        \
      float pp = w2[0] * HH2[jo] + w2[1] * HH2[jo + 1] + w2[2] * HH2[jo + 2]   \
               + w2[3] * HH1[jo] + w2[4] * HH1[jo + 1] + w2[5] * HH1[jo + 2]   \
               + w2[6] * HH0[jo] + w2[7] * HH0[jo + 1] + w2[8] * HH0[jo + 2];  \
      partW[jo][lane] = pp;                                                    \
    }                                                                          \
    {                                                                          \
      const float4* pr = (const float4*)&partW[pq][qq * 16];                   \
      float cg_ = cost[obase + (size_t)(T) * W];                               \
      float4 v0 = pr[0], v1 = pr[1];                                           \
      float s_ = ((v0.x + v0.y) + (v0.z + v0.w)) +                             \
                 ((v1.x + v1.y) + (v1.z + v1.w));                              \
      float4 v2 = pr[2], v3 = pr[3];                                           \
      s_ += ((v2.x + v2.y) + (v2.z + v2.w)) +                                  \
            ((v3.x + v3.y) + (v3.z + v3.w));                                   \
      s_ += __shfl_xor(s_, 16);                                                \
      s_ += __shfl_xor(s_, 32);                                                \
      if (qq == 0) bout[obase + (size_t)(T) * W] = cg_ + s_ + b2;              \
    }                                                                          \
  }

#define STEP(T, AIN, AOUT, HX2, HX1, HX0, B0, B1, B2, BN, DOLOAD, DOBEL)       \
  {                                                                            \
    if (DOBEL) { LOADBEL(y0 + (T) + 3, BN); }                                  \
    if (DOLOAD) { LOADROW(y0 + (T) + 2, AOUT); }                               \
    COMPUTE((T) + 1, AIN, HX0, B0, B1, B2);                                    \
    EMIT3(T, HX2, HX1, HX0);                                                   \
  }

__global__ __launch_bounds__(256, 4) void mp_iter_fast(
    const float* __restrict__ At,    // [HW][64]
    const float* __restrict__ cost,
    const float* __restrict__ bin,
    float* __restrict__ bout,
    const float* __restrict__ mp_w1,
    const float* __restrict__ mp_w2,
    const float* __restrict__ mp_b2) {
    __shared__ float partS[4][16][68];

    const int tid = threadIdx.x;
    const int lane = tid & 63;       // = hid
    const int lw = __builtin_amdgcn_readfirstlane(tid >> 6);
    float (*partW)[68] = partS[lw];

    const int i = blockIdx.x;
    const int xcd = i & 7;
    const int jj = i >> 3;           // 0..255
    const int ybl = jj & 1;
    const int sl = (jj >> 1) & 15;
    const int d4 = jj >> 5;          // 0..7
    const int d = d4 * 4 + lw;
    const int x0 = sl * 16;
    const int y0 = (xcd + 8 * ybl) * 8;
    const bool xnot0 = (x0 > 0), xnotE = (x0 < W - 16);

    float w1[9], w2[9];
#pragma unroll
    for (int k = 0; k < 9; k++) {
        w1[k] = mp_w1[lane * 297 + 288 + k];
        w2[k] = mp_w2[lane * 9 + k];
    }
    const float b2 = mp_b2[0];

    const float* bp = At + (size_t)(y0 - 1) * (W * 64) + (x0 + 7) * 64 + lane;
    const int e0off  = (x0 == 0)      ? -448 : -512;
    const int e17off = (x0 == W - 16) ?  512 :  576;

    const float* beld = bin + (size_t)d * HW;
    const int pq = lane & 15, qq = lane >> 4;
    const size_t obase = (size_t)d * HW + (size_t)y0 * W + x0 + pq;

    float aA[18], aB[18];
    float hA[18], hB[18], hC[18];
    float bl0[20], bl1[20], bl2[20], bl3[20];

    LOADBEL(y0 - 2, bl0);
    LOADBEL(y0 - 1, bl1);
    LOADBEL(y0,     bl2);
    LOADROW(y0 - 1, aA);
    LOADROW(y0,     aB);
    COMPUTE(-1, aA, hA, bl0, bl1, bl2);
    LOADBEL(y0 + 1, bl3);
    LOADROW(y0 + 1, aA);
    COMPUTE(0, aB, hB, bl1, bl2, bl3);
    LOADBEL(y0 + 2, bl0);

    STEP(0, aA, aB, hA, hB, hC, bl2, bl3, bl0, bl1, 1, 1)
    STEP(1, aB, aA, hB, hC, hA, bl3, bl0, bl1, bl2, 1, 1)
    STEP(2, aA, aB, hC, hA, hB, bl0, bl1, bl2, bl3, 1, 1)
    STEP(3, aB, aA, hA, hB, hC, bl1, bl2, bl3, bl0, 1, 1)
    STEP(4, aA, aB, hB, hC, hA, bl2, bl3, bl0, bl1, 1, 1)
    STEP(5, aB, aA, hC, hA, hB, bl3, bl0, bl1, bl2, 1, 1)
    STEP(6, aA, aB, hA, hB, hC, bl0, bl1, bl2, bl3, 1, 1)
    STEP(7, aB, aA, hB, hC, hA, bl1, bl2, bl3, bl0, 0, 0)
}

// ---------------- softmax over D of -belief + disparity + x4 concat fused ----------------
__global__ void softmax_disp(const float* __restrict__ bel, const float* __restrict__ left,
                             float* __restrict__ disp, float* __restrict__ x4) {
    int p = blockIdx.x * 256 + threadIdx.x;
    if (p >= HW) return;
    float v[ND];
    float m = -1e30f;
#pragma unroll
    for (int d = 0; d < ND; d++) {
        v[d] = -bel[d * HW + p];
        m = fmaxf(m, v[d]);
    }
    float s = 0.f, ws = 0.f;
#pragma unroll
    for (int d = 0; d < ND; d++) {
        float e = __expf(v[d] - m);
        s += e;
        ws += e * (float)d;
    }
    float dv = ws / s;
    disp[p] = dv;
    x4[3 * HW + p] = dv;
    x4[p] = left[p];
    x4[HW + p] = left[HW + p];
    x4[2 * HW + p] = left[2 * HW + p];
}

extern "C" void kernel_launch(void* const* d_in, const int* in_sizes, int n_in,
                              void* d_out, int out_size, void* d_ws, size_t ws_size,
                              hipStream_t stream) {
    const float* left   = (const float*)d_in[0];
    const float* right  = (const float*)d_in[1];
    const float* fe_w1  = (const float*)d_in[2];
    const float* fe_b1  = (const float*)d_in[3];
    const float* fe_w2  = (const float*)d_in[4];
    const float* fe_b2  = (const float*)d_in[5];
    const float* cv_w   = (const float*)d_in[6];
    const float* cv_b   = (const float*)d_in[7];
    const float* mp_w1  = (const float*)d_in[8];
    const float* mp_b1  = (const float*)d_in[9];
    const float* mp_w2  = (const float*)d_in[10];
    const float* mp_b2  = (const float*)d_in[11];
    const float* rf_w1  = (const float*)d_in[12];
    const float* rf_b1  = (const float*)d_in[13];
    const float* rf_w2  = (const float*)d_in[14];
    const float* rf_b2  = (const float*)d_in[15];
    const float* rf_w3  = (const float*)d_in[16];
    const float* rf_b3  = (const float*)d_in[17];
    float* out = (float*)d_out;

    float* ws = (float*)d_ws;
    float* At    = ws;
    float* tmp0  = ws;               // tmp0/tmp1 alias At region, consumed before aconv writes At
    float* tmp1  = ws + 1048576;
    float* lf    = ws + 2097152;
    float* rfeat = ws + 3145728;
    float* cost  = ws + 4194304;
    float* bel   = ws + 5242880;
    float* bel2  = ws + 6291456;
    float* disp  = ws + 7405568;
    float* x4    = ws + 7438336;
    float* r1    = ws + 7569408;

    dim3 blk(256);

    // feature extraction: NCO=4 -> 2048 blocks (8 blocks/CU)
    conv3x3<4><<<dim3(8, 16, 16), blk, 0, stream>>>(left, right, tmp0, tmp1, fe_w1, fe_b1, 3, 32, 27, 1, nullptr, 0);
    conv3x3<4><<<dim3(8, 16, 16), blk, 0, stream>>>(tmp0, tmp1, lf, rfeat, fe_w2, fe_b2, 32, 32, 288, 1, nullptr, 0);

    // A-conv: lane=cout, coalesced transposed write into At [p][hid]
    aconv<<<dim3(1024), blk, 0, stream>>>(lf, At, mp_w1, mp_b1);

    // fused channel-dot + cost expand + belief init
    chan_cost<<<dim3(H), blk, 0, stream>>>(lf, rfeat, cv_w, cv_b, cost, bel);

    // 5 MP iterations — 2048 blocks x 256 threads
    dim3 gmp(2048);
    mp_iter_fast<<<gmp, blk, 0, stream>>>(At, cost, bel,  bel2, mp_w1, mp_w2, mp_b2);
    mp_iter_fast<<<gmp, blk, 0, stream>>>(At, cost, bel2, bel,  mp_w1, mp_w2, mp_b2);
    mp_iter_fast<<<gmp, blk, 0, stream>>>(At, cost, bel,  bel2, mp_w1, mp_w2, mp_b2);
    mp_iter_fast<<<gmp, blk, 0, stream>>>(At, cost, bel2, bel,  mp_w1, mp_w2, mp_b2);
    mp_iter_fast<<<gmp, blk, 0, stream>>>(At, cost, bel,  bel2, mp_w1, mp_w2, mp_b2);

    softmax_disp<<<dim3(HW / 256), blk, 0, stream>>>(bel2, left, disp, x4);

    // refinement: conv3x3<4> for rf1/rf2; rf3 legacy with fused residual add
    conv3x3<4><<<dim3(8, 16, 8), blk, 0, stream>>>(x4, x4, r1, r1, rf_w1, rf_b1, 4, 32, 36, 1, nullptr, 0);
    conv3x3<4><<<dim3(8, 16, 8), blk, 0, stream>>>(r1, r1, rfeat, rfeat, rf_w2, rf_b2, 32, 32, 288, 1, nullptr, 0);
    conv3x3<4><<<dim3(8, 16, 1), blk, 0, stream>>>(rfeat, rfeat, out, out, rf_w3, rf_b3, 32, 1, 288, 0, disp, 0);
}